// Round 4
// baseline (954.481 us; speedup 1.0000x reference)
//
#include <hip/hip_runtime.h>
#include <hip/hip_bf16.h>

// R-GCN 2-layer forward, fully fused per layer:
//   sort edges by (dst*8+etype) -> per-(node,relation) contiguous buckets.
//   fused_layer: per 128-node block, loop r=0..8 (8 relations + self-loop):
//     aggregate bf16 h[src] rows into LDS A-tile (fp32 acc in regs),
//     stage W_r tile, MFMA K=128 chunk, accumulate in AGPRs across chunks.
//   No ACC[N][1152] materialization -> saves ~920 MB HBM vs round-3 version.

#define D 128
#define ELDS 2560    // staged edge indices per block (mean ~2048, 11-sigma margin)

typedef __attribute__((ext_vector_type(8))) __bf16 bf16x8;
typedef __attribute__((ext_vector_type(8))) unsigned short us8;
typedef __attribute__((ext_vector_type(4))) unsigned short us4;
typedef __attribute__((ext_vector_type(4))) float f32x4;

__device__ __forceinline__ unsigned short f2bf(float f) {
    union { float f; unsigned u; } v; v.f = f;
    unsigned r = v.u + 0x7FFF + ((v.u >> 16) & 1);   // RNE
    return (unsigned short)(r >> 16);
}

__device__ __forceinline__ void acc4(float4& a, us4 r) {
    a.x += __uint_as_float((unsigned)r.x << 16);
    a.y += __uint_as_float((unsigned)r.y << 16);
    a.z += __uint_as_float((unsigned)r.z << 16);
    a.w += __uint_as_float((unsigned)r.w << 16);
}

// LDS tile: 128 rows x 16 chunks of 8 bf16; chunk' = c ^ (row&15) balances banks.
__device__ __forceinline__ int eoff(int row, int c) {
    return row * 128 + ((c ^ (row & 15)) << 3);
}

// ---------------- sort: histogram / hierarchical scan / scatter ----------------

__global__ void hist_kernel(const int* __restrict__ dst, const int* __restrict__ et,
                            int* __restrict__ cnt, int E) {
    int e = blockIdx.x * blockDim.x + threadIdx.x;
    if (e < E) atomicAdd(&cnt[dst[e] * 8 + et[e]], 1);
}

__global__ __launch_bounds__(256) void scan_partial(const int* __restrict__ cnt,
                                                    int* __restrict__ part, int B) {
    int t = threadIdx.x;
    int base = blockIdx.x * 1024 + t * 4;
    int4 v = {0, 0, 0, 0};
    if (base + 3 < B) v = *(const int4*)(cnt + base);
    else {
        if (base     < B) v.x = cnt[base];
        if (base + 1 < B) v.y = cnt[base + 1];
        if (base + 2 < B) v.z = cnt[base + 2];
        if (base + 3 < B) v.w = cnt[base + 3];
    }
    int s = v.x + v.y + v.z + v.w;
    #pragma unroll
    for (int off = 32; off; off >>= 1) s += __shfl_down(s, off, 64);
    __shared__ int ws[4];
    int lane = t & 63, w = t >> 6;
    if (lane == 0) ws[w] = s;
    __syncthreads();
    if (t == 0) part[blockIdx.x] = ws[0] + ws[1] + ws[2] + ws[3];
}

// root scan of <=1024 partials
__global__ __launch_bounds__(1024) void scan_root(int* __restrict__ part,
                                                  int* __restrict__ total, int NB) {
    int t = threadIdx.x;
    int v = (t < NB) ? part[t] : 0;
    int lane = t & 63, w = t >> 6;   // 16 waves
    int inc = v;
    #pragma unroll
    for (int off = 1; off < 64; off <<= 1) {
        int n = __shfl_up(inc, off, 64);
        if (lane >= off) inc += n;
    }
    __shared__ int ws[16];
    if (lane == 63) ws[w] = inc;
    __syncthreads();
    int wbase = 0;
    for (int i = 0; i < w; ++i) wbase += ws[i];
    if (t < NB) part[t] = wbase + inc - v;
    if (t == NB - 1) *total = wbase + inc;
}

__global__ __launch_bounds__(256) void scan_final(const int* __restrict__ cnt,
                                                  const int* __restrict__ part,
                                                  int* __restrict__ offs,
                                                  int* __restrict__ head, int B) {
    int t = threadIdx.x;
    int base = blockIdx.x * 1024 + t * 4;
    int4 v = {0, 0, 0, 0};
    if (base + 3 < B) v = *(const int4*)(cnt + base);
    else {
        if (base     < B) v.x = cnt[base];
        if (base + 1 < B) v.y = cnt[base + 1];
        if (base + 2 < B) v.z = cnt[base + 2];
        if (base + 3 < B) v.w = cnt[base + 3];
    }
    int tsum = v.x + v.y + v.z + v.w;
    int lane = t & 63, w = t >> 6;
    int inc = tsum;
    #pragma unroll
    for (int off = 1; off < 64; off <<= 1) {
        int n = __shfl_up(inc, off, 64);
        if (lane >= off) inc += n;
    }
    __shared__ int ws[4];
    if (lane == 63) ws[w] = inc;
    __syncthreads();
    int wbase = 0;
    for (int i = 0; i < w; ++i) wbase += ws[i];
    int run = part[blockIdx.x] + wbase + inc - tsum;
    int4 o = {run, run + v.x, run + v.x + v.y, run + v.x + v.y + v.z};
    if (base + 3 < B) {
        *(int4*)(offs + base) = o;
        *(int4*)(head + base) = o;
    } else {
        if (base     < B) { offs[base]     = o.x; head[base]     = o.x; }
        if (base + 1 < B) { offs[base + 1] = o.y; head[base + 1] = o.y; }
        if (base + 2 < B) { offs[base + 2] = o.z; head[base + 2] = o.z; }
        if (base + 3 < B) { offs[base + 3] = o.w; head[base + 3] = o.w; }
    }
}

__global__ void scatter_kernel(const int* __restrict__ src, const int* __restrict__ dst,
                               const int* __restrict__ et, int* __restrict__ head,
                               int* __restrict__ sorted, int E) {
    int e = blockIdx.x * blockDim.x + threadIdx.x;
    if (e < E) {
        int pos = atomicAdd(&head[dst[e] * 8 + et[e]], 1);
        sorted[pos] = src[e];
    }
}

// ---------------- weight cast to r-major packed bf16: Bp[(r*128+o)*128 + i] ----------------

__global__ void castB_kernel(const float* __restrict__ W1, const float* __restrict__ lw1,
                             const float* __restrict__ W2, const float* __restrict__ lw2,
                             unsigned short* __restrict__ B1, unsigned short* __restrict__ B2) {
    int idx = blockIdx.x * blockDim.x + threadIdx.x;
    const int per = 1152 * 128;
    if (idx >= 2 * per) return;
    int layer = idx / per;
    int rem = idx - layer * per;
    int k = rem >> 7;        // r*128 + i, 0..1151
    int o = rem & 127;       // coalesced read dim
    const float* W  = layer ? W2 : W1;
    const float* lw = layer ? lw2 : lw1;
    float val = (k < 1024) ? W[k * D + o] : lw[(k - 1024) * D + o];
    unsigned short* Bp = layer ? B2 : B1;
    int r = k >> 7, i = k & 127;
    Bp[((r * 128 + o) << 7) + i] = f2bf(val);
}

__global__ void castH_kernel(const float* __restrict__ h, unsigned short* __restrict__ hb, int n4) {
    int i = blockIdx.x * blockDim.x + threadIdx.x;
    if (i < n4) {
        float4 v = *(const float4*)(h + (size_t)i * 4);
        us4 o; o.x = f2bf(v.x); o.y = f2bf(v.y); o.z = f2bf(v.z); o.w = f2bf(v.w);
        *(us4*)(hb + (size_t)i * 4) = o;
    }
}

// ---------------- fused aggregate + GEMM layer ----------------

__global__ __launch_bounds__(256, 2) void fused_layer(
        const unsigned short* __restrict__ hb,     // bf16 node features [N][128]
        const int* __restrict__ offs,              // bucket offsets [N*8+1]
        const int* __restrict__ sorted,            // src per edge, bucket-sorted
        const unsigned short* __restrict__ Bp,     // packed weights [9*128][128] bf16
        const float* __restrict__ bias,
        float* __restrict__ outf,                  // fp32 out (layer 2)
        unsigned short* __restrict__ outb,         // bf16 out (layer 1)
        int N, int relu_bf)
{
    __shared__ unsigned short At[128 * 128];   // 32 KB
    __shared__ unsigned short Bt[128 * 128];   // 32 KB
    __shared__ int elds[ELDS];                 // 10 KB
    __shared__ int offsl[1025];                // 4 KB  -> 79.9 KB total, 2 blocks/CU

    const int t = threadIdx.x;
    const int lane = t & 63;
    const int w = t >> 6;
    const int half = lane >> 5;
    const int l32 = lane & 31;
    const int c4 = l32 * 4;
    const int quad = lane >> 4;
    const int c16 = lane & 15;
    const int v0 = blockIdx.x * 128;
    const int B = N * 8;

    // stage this block's bucket offsets and edge-src indices
    for (int i = t; i < 1025; i += 256) {
        int gi = v0 * 8 + i; if (gi > B) gi = B;
        offsl[i] = offs[gi];
    }
    const int ebase = offs[v0 * 8];
    const int vend = (v0 + 128 < N) ? (v0 + 128) : N;
    const int ecnt = offs[vend * 8] - ebase;
    const int scnt = (ecnt < ELDS) ? ecnt : ELDS;
    for (int i = t; i < scnt; i += 256)
        elds[i] = sorted[ebase + i];
    __syncthreads();

    f32x4 acc[2][8];
    #pragma unroll
    for (int a = 0; a < 2; ++a)
        #pragma unroll
        for (int b = 0; b < 8; ++b) acc[a][b] = f32x4{0.f, 0.f, 0.f, 0.f};

    for (int r = 0; r < 9; ++r) {
        // stage W_r tile: contiguous 32 KB, 256 threads x 128 B
        {
            const unsigned short* bsrc = Bp + r * 16384;
            int row = t >> 1;
            int cb = (t & 1) * 8;
            #pragma unroll
            for (int j = 0; j < 8; ++j) {
                us8 vv = *(const us8*)(bsrc + (row << 7) + ((cb + j) << 3));
                *(us8*)(Bt + eoff(row, cb + j)) = vv;
            }
        }
        // aggregate relation r for this block's 128 nodes (wave = 2 nodes in flight)
        for (int i = 0; i < 16; ++i) {
            int rv = w * 32 + i * 2 + half;
            int v = v0 + rv;
            float4 a = {0.f, 0.f, 0.f, 0.f};
            if (v < N) {
                if (r < 8) {
                    int e0 = offsl[rv * 8 + r];
                    int e1 = offsl[rv * 8 + r + 1];
                    int e = e0;
                    while (e + 1 < e1) {
                        int i0 = e - ebase;
                        int s0 = (i0 < ELDS)     ? elds[i0]     : sorted[e];
                        int s1 = (i0 + 1 < ELDS) ? elds[i0 + 1] : sorted[e + 1];
                        us4 h0 = *(const us4*)(hb + (size_t)s0 * D + c4);
                        us4 h1 = *(const us4*)(hb + (size_t)s1 * D + c4);
                        acc4(a, h0); acc4(a, h1);
                        e += 2;
                    }
                    if (e < e1) {
                        int i0 = e - ebase;
                        int s0 = (i0 < ELDS) ? elds[i0] : sorted[e];
                        us4 h0 = *(const us4*)(hb + (size_t)s0 * D + c4);
                        acc4(a, h0);
                    }
                } else {
                    us4 hv = *(const us4*)(hb + (size_t)v * D + c4);   // self-loop
                    acc4(a, hv);
                }
            }
            us4 o; o.x = f2bf(a.x); o.y = f2bf(a.y); o.z = f2bf(a.z); o.w = f2bf(a.w);
            *(us4*)(At + eoff(rv, l32 >> 1) + (c4 & 7)) = o;
        }
        __syncthreads();

        // MFMA: K=128 chunk for this relation
        #pragma unroll
        for (int ks = 0; ks < 4; ++ks) {
            int kc = ks * 4 + quad;
            bf16x8 af0 = *(const bf16x8*)(At + eoff(w * 32 + c16, kc));
            bf16x8 af1 = *(const bf16x8*)(At + eoff(w * 32 + 16 + c16, kc));
            #pragma unroll
            for (int ct = 0; ct < 8; ++ct) {
                bf16x8 bfr = *(const bf16x8*)(Bt + eoff(ct * 16 + c16, kc));
                acc[0][ct] = __builtin_amdgcn_mfma_f32_16x16x32_bf16(af0, bfr, acc[0][ct], 0, 0, 0);
                acc[1][ct] = __builtin_amdgcn_mfma_f32_16x16x32_bf16(af1, bfr, acc[1][ct], 0, 0, 0);
            }
        }
        __syncthreads();
    }

    // epilogue: C[row=quad*4+i][col=c16] per 16x16 tile (m89-verified layout)
    #pragma unroll
    for (int rt = 0; rt < 2; ++rt) {
        int row0 = v0 + w * 32 + rt * 16 + quad * 4;
        #pragma unroll
        for (int ct = 0; ct < 8; ++ct) {
            int col = ct * 16 + c16;
            float bcol = bias[col];
            #pragma unroll
            for (int i2 = 0; i2 < 4; ++i2) {
                int rr = row0 + i2;
                if (rr < N) {
                    float vv = acc[rt][ct][i2] + bcol;
                    if (relu_bf) {
                        vv = fmaxf(vv, 0.f);
                        outb[(size_t)rr * D + col] = f2bf(vv);
                    } else {
                        outf[(size_t)rr * D + col] = vv;
                    }
                }
            }
        }
    }
}

// ---------------- launch ----------------

extern "C" void kernel_launch(void* const* d_in, const int* in_sizes, int n_in,
                              void* d_out, int out_size, void* d_ws, size_t ws_size,
                              hipStream_t stream) {
    const float* feats = (const float*)d_in[0];
    const float* W1    = (const float*)d_in[1];
    const float* lw1   = (const float*)d_in[2];
    const float* b1    = (const float*)d_in[3];
    const float* W2    = (const float*)d_in[4];
    const float* lw2   = (const float*)d_in[5];
    const float* b2    = (const float*)d_in[6];
    const int*   src   = (const int*)d_in[7];
    const int*   dst   = (const int*)d_in[8];
    const int*   etype = (const int*)d_in[9];
    const int N = in_sizes[0] / D;
    const int E = in_sizes[7];
    const int B = N * 8;
    float* out = (float*)d_out;

    size_t woff = 0;
    auto take = [&](size_t bytes) -> void* {
        void* p = (char*)d_ws + woff;
        woff += (bytes + 255) & ~(size_t)255;
        return p;
    };
    int* cnt            = (int*)take((size_t)B * 4);
    int* offs           = (int*)take((size_t)(B + 1) * 4);
    int* head           = (int*)take((size_t)B * 4);
    int* part           = (int*)take((size_t)1024 * 4);
    int* sorted         = (int*)take((size_t)E * 4);
    unsigned short* Bp1 = (unsigned short*)take((size_t)1152 * 128 * 2);
    unsigned short* Bp2 = (unsigned short*)take((size_t)1152 * 128 * 2);
    unsigned short* hb0 = (unsigned short*)take((size_t)N * D * 2);
    unsigned short* hb1 = (unsigned short*)take((size_t)N * D * 2);

    (void)hipMemsetAsync(cnt, 0, (size_t)B * 4, stream);

    int eb = (E + 255) / 256;
    hist_kernel<<<eb, 256, 0, stream>>>(dst, etype, cnt, E);

    int NB = (B + 1023) / 1024;   // 782 <= 1024
    scan_partial<<<NB, 256, 0, stream>>>(cnt, part, B);
    scan_root<<<1, 1024, 0, stream>>>(part, offs + B, NB);
    scan_final<<<NB, 256, 0, stream>>>(cnt, part, offs, head, B);

    scatter_kernel<<<eb, 256, 0, stream>>>(src, dst, etype, head, sorted, E);

    int cb = (2 * 1152 * 128 + 255) / 256;
    castB_kernel<<<cb, 256, 0, stream>>>(W1, lw1, W2, lw2, Bp1, Bp2);

    int n4 = N * D / 4;
    castH_kernel<<<(n4 + 255) / 256, 256, 0, stream>>>(feats, hb0, n4);

    int gb = (N + 127) / 128;
    // layer 1: hb0 -> hb1 (bf16, relu)
    fused_layer<<<gb, 256, 0, stream>>>(hb0, offs, sorted, Bp1, b1, out, hb1, N, 1);
    // layer 2: hb1 -> d_out (fp32)
    fused_layer<<<gb, 256, 0, stream>>>(hb1, offs, sorted, Bp2, b2, out, hb1, N, 0);
}